// Round 1
// baseline (233.893 us; speedup 1.0000x reference)
//
#include <hip/hip_runtime.h>

// DNA transport NEGF: per (b,e) invert A = (E*I - H) + i*diag(0.5*(gL+gR)),
// DOS = -Im tr(Gr), T = sum_ij gL_i gR_j |Gr_ij|^2, plus H scatter output.
//
// Layout: lane j of a 20-lane subgroup owns column j of A (in-place
// Gauss-Jordan -> same registers end as column j of Gr). 3 subgroups per
// wave, 4 waves (12 matrices) per 256-thread block, one block per batch b,
// 9 chunks x 12 = 108 slots for 100 energies.
//
// No pivoting: imag(x^* A x) = x^* diag(0.5(gL+gR)) x > 0 for all leading
// blocks => every pivot magnitude >= min_i 0.5(gL_i+gR_i). Stable in fp32.

#define H_N   20
#define NE    100
#define T_OFF 0
#define D_OFF 102400
#define H_OFF 204800

__device__ __forceinline__ int triIdx(int i, int j) {  // i <= j, row-major triu
    return i * H_N - ((i * (i - 1)) >> 1) + (j - i);
}

__global__ __launch_bounds__(256, 2)
void negf_all(const float* __restrict__ tri,
              const float* __restrict__ GL,
              const float* __restrict__ GR,
              float* __restrict__ out)
{
    __shared__ float Hcm[400];          // column-major: Hcm[c*20 + r] = H[r][c]
    __shared__ float sgL[H_N], sgR[H_N], sgam[H_N];
    __shared__ float4 stage[12][10];    // per-subgroup column broadcast

    const int b   = blockIdx.x;
    const int tid = threadIdx.x;

    // ---- stage H (column-major) + gammas into LDS ----
    const float* triB = tri + b * 210;
    #pragma unroll
    for (int u0 = 0; u0 < 2; ++u0) {
        int u = tid + u0 * 256;
        if (u < 400) {
            int c = u / 20, r = u - c * 20;
            int lo = r < c ? r : c;
            int hi = r < c ? c : r;
            Hcm[u] = triB[triIdx(lo, hi)];
        }
    }
    if (tid < H_N) {
        float l = GL[b * H_N + tid];
        float r = GR[b * H_N + tid];
        sgL[tid] = l; sgR[tid] = r; sgam[tid] = 0.5f * (l + r);
    }
    __syncthreads();

    // ---- H output (row-major), exact copy of inputs ----
    #pragma unroll
    for (int u0 = 0; u0 < 2; ++u0) {
        int u = tid + u0 * 256;
        if (u < 400) {
            int r = u / 20, c = u - r * 20;
            out[H_OFF + b * 400 + u] = Hcm[c * 20 + r];
        }
    }

    const int lane = tid & 63;
    const int wid  = tid >> 6;
    const int sw   = lane / 20;              // 0..2 active, 3 idle
    const int ll   = lane - sw * 20;         // 0..19 row/col id within subgroup
    const int sg   = wid * 3 + (sw < 3 ? sw : 0);
    const bool lv  = (sw < 3);

    const float gj   = sgR[ll];              // gammaR_j for this lane's column
    const float gamj = sgam[ll];

    #pragma unroll 1
    for (int chunk = 0; chunk < 9; ++chunk) {
        const int e = chunk * 12 + sg;
        const bool active = lv && (e < NE);
        if (!active) continue;

        const float E = fmaf((float)e, 6.0f / 99.0f, -3.0f);

        // build column ll of A
        float2 col[H_N];
        #pragma unroll
        for (int i = 0; i < H_N; ++i) {
            float hv = Hcm[ll * 20 + i];
            col[i].x = (i == ll) ? (E - hv) : (-hv);
            col[i].y = (i == ll) ? gamj : 0.0f;
        }

        // ---- in-place Gauss-Jordan, fully unrolled (static reg indices) ----
        #pragma unroll
        for (int k = 0; k < H_N; ++k) {
            // lane k publishes its (pre-update) column
            if (ll == k) {
                #pragma unroll
                for (int q = 0; q < 10; ++q)
                    stage[sg][q] = make_float4(col[2*q].x,   col[2*q].y,
                                               col[2*q+1].x, col[2*q+1].y);
            }
            __builtin_amdgcn_wave_barrier();
            float2 y[H_N];
            #pragma unroll
            for (int q = 0; q < 10; ++q) {
                float4 v = stage[sg][q];
                y[2*q].x   = v.x; y[2*q].y   = v.y;
                y[2*q+1].x = v.z; y[2*q+1].y = v.w;
            }
            __builtin_amdgcn_wave_barrier();

            // p = 1 / pivot (complex reciprocal)
            const float den = fmaf(y[k].x, y[k].x, y[k].y * y[k].y);
            const float inv = __builtin_amdgcn_rcpf(den);
            const float px  =  y[k].x * inv;
            const float py  = -y[k].y * inv;

            // t = col[k] * p ; lane k uses t = 1 + p (e_k substitution folded in)
            float tx = col[k].x * px - col[k].y * py;
            float ty = col[k].x * py + col[k].y * px;
            const bool isk  = (ll == k);
            const float tux = isk ? (1.0f + px) : tx;
            const float tuy = isk ? py          : ty;
            const float fkx = isk ? px : tx;    // final col[k]
            const float fky = isk ? py : ty;

            #pragma unroll
            for (int i = 0; i < H_N; ++i) {
                if (i == k) continue;
                col[i].x = fmaf(-y[i].x, tux, fmaf( y[i].y, tuy, col[i].x));
                col[i].y = fmaf(-y[i].x, tuy, fmaf(-y[i].y, tux, col[i].y));
            }
            col[k].x = fkx;
            col[k].y = fky;
        }

        // ---- epilogue: T partial + diag Im, subgroup reduce, store ----
        float tv = 0.0f, dv = 0.0f;
        #pragma unroll
        for (int i = 0; i < H_N; ++i) {
            float aa = fmaf(col[i].x, col[i].x, col[i].y * col[i].y);
            tv = fmaf(sgL[i], aa, tv);
            dv = (i == ll) ? col[i].y : dv;
        }
        tv *= gj;

        #pragma unroll
        for (int d = 16; d >= 1; d >>= 1) {
            float t2 = __shfl(tv, lane + d, 64);
            float d2 = __shfl(dv, lane + d, 64);
            if (ll + d < 20) { tv += t2; dv += d2; }
        }
        if (ll == 0) {
            out[T_OFF + b * NE + e] = __log10f(fmaxf(tv, 1e-16f));
            out[D_OFF + b * NE + e] = __log10f(fmaxf(-dv, 1e-16f));
        }
    }
}

extern "C" void kernel_launch(void* const* d_in, const int* in_sizes, int n_in,
                              void* d_out, int out_size, void* d_ws, size_t ws_size,
                              hipStream_t stream) {
    const float* tri = (const float*)d_in[0];
    const float* gL  = (const float*)d_in[1];
    const float* gR  = (const float*)d_in[2];
    float* out = (float*)d_out;
    negf_all<<<1024, 256, 0, stream>>>(tri, gL, gR, out);
}